// Round 12
// baseline (36.736 us; speedup 1.0000x reference)
//
#include <hip/hip_runtime.h>

#define TPB 256
#define MPW 256               // matrices per wave tile (4 per lane)
#define FPW (MPW * 9)         // 2304 floats = 9216 B per wave region
#define MPB (MPW * 4)         // 1024 matrices per block

typedef float v4f __attribute__((ext_vector_type(4)));
typedef int   v4i __attribute__((ext_vector_type(4)));

static __device__ __forceinline__ v4f sqrt4(v4f a){
    v4f r; r.x=__builtin_amdgcn_sqrtf(a.x); r.y=__builtin_amdgcn_sqrtf(a.y);
    r.z=__builtin_amdgcn_sqrtf(a.z); r.w=__builtin_amdgcn_sqrtf(a.w); return r;
}
static __device__ __forceinline__ v4f rsq4(v4f a){
    v4f r; r.x=__builtin_amdgcn_rsqf(a.x); r.y=__builtin_amdgcn_rsqf(a.y);
    r.z=__builtin_amdgcn_rsqf(a.z); r.w=__builtin_amdgcn_rsqf(a.w); return r;
}
static __device__ __forceinline__ v4f csign4(v4f x, v4f y){
    v4f r; r.x=copysignf(x.x,y.x); r.y=copysignf(x.y,y.y);
    r.z=copysignf(x.z,y.z); r.w=copysignf(x.w,y.w); return r;
}
static __device__ __forceinline__ v4f fabs4(v4f x){
    v4f r; r.x=fabsf(x.x); r.y=fabsf(x.y); r.z=fabsf(x.z); r.w=fabsf(x.w); return r;
}
static __device__ __forceinline__ v4f sel4(v4i m, v4f a, v4f b){
    v4f r; r.x=m.x?a.x:b.x; r.y=m.y?a.y:b.y; r.z=m.z?a.z:b.z; r.w=m.w?a.w:b.w; return r;
}
static __device__ __forceinline__ void rot4(v4f &p, v4f &q, v4f c, v4f s){
    v4f x = p, y = q; p = c*x - s*y; q = s*x + c*y;
}

// Exact cyclic-Jacobi rotation (2 transcendental groups), branchless.
// Same math as rounds 7-11, widened to 4 independent lanes-in-registers:
// <4 x float> arithmetic lowers to PAIRS of v_pk_fma_f32 -> two independent
// packed dependency chains interleaved at instruction level (2x ILP).
static __device__ __forceinline__ void jrot4(v4f &app, v4f &aqq, v4f &apq,
                                             v4f &arp, v4f &arq,
                                             v4f &v0p, v4f &v1p, v4f &v2p,
                                             v4f &v0q, v4f &v1q, v4f &v2q)
{
    v4f d   = aqq - app;
    v4f w   = apq + apq;
    v4f nrm = d*d + w*w;
    v4f rr  = sqrt4(nrm);
    v4f sr  = csign4(rr, d);
    v4f den = d + sr;
    v4f inv = rsq4(den*den + w*w);
    v4f c   = fabs4(den) * inv;
    v4f s   = w * csign4(inv, den);
    v4i tiny = nrm < (v4f)1e-30f;
    c = sel4(tiny, (v4f)1.0f, c);
    s = sel4(tiny, (v4f)0.0f, s);
    v4f sum = app + aqq;
    v4f lo  = 0.5f*(sum - sr);
    app = lo; aqq = sum - lo; apq = (v4f)0.0f;
    rot4(arp, arq, c, s);
    rot4(v0p, v0q, c, s);
    rot4(v1p, v1q, c, s);
    rot4(v2p, v2q, c, s);
}

// SO(3) projection for 4 packed matrices (same algorithm as r7-r11):
// V from 3 Jacobi sweeps; U via Gram-Schmidt on b1,b2 + u3 = u1 x u2.
static __device__ __forceinline__ void solve4(
    v4f m00, v4f m01, v4f m02,
    v4f m10, v4f m11, v4f m12,
    v4f m20, v4f m21, v4f m22,
    v4f &r00, v4f &r01, v4f &r02,
    v4f &r10, v4f &r11, v4f &r12,
    v4f &r20, v4f &r21, v4f &r22)
{
    v4f a00 = m00*m00 + m10*m10 + m20*m20;
    v4f a11 = m01*m01 + m11*m11 + m21*m21;
    v4f a22 = m02*m02 + m12*m12 + m22*m22;
    v4f a01 = m00*m01 + m10*m11 + m20*m21;
    v4f a02 = m00*m02 + m10*m12 + m20*m22;
    v4f a12 = m01*m02 + m11*m12 + m21*m22;

    v4f v00 = (v4f)1.0f, v01 = (v4f)0.0f, v02 = (v4f)0.0f;
    v4f v10 = (v4f)0.0f, v11 = (v4f)1.0f, v12 = (v4f)0.0f;
    v4f v20 = (v4f)0.0f, v21 = (v4f)0.0f, v22 = (v4f)1.0f;

    #pragma unroll
    for (int sw = 0; sw < 3; ++sw) {
        jrot4(a00, a11, a01, a02, a12, v00, v10, v20, v01, v11, v21);
        jrot4(a00, a22, a02, a01, a12, v00, v10, v20, v02, v12, v22);
        jrot4(a11, a22, a12, a01, a02, v01, v11, v21, v02, v12, v22);
    }

    v4f t;
    {
        v4i c01 = a00 < a11;
        t = a00; a00 = sel4(c01, a11, a00); a11 = sel4(c01, t, a11);
        t = v00; v00 = sel4(c01, v01, v00); v01 = sel4(c01, -t, v01);
        t = v10; v10 = sel4(c01, v11, v10); v11 = sel4(c01, -t, v11);
        t = v20; v20 = sel4(c01, v21, v20); v21 = sel4(c01, -t, v21);
    }
    {
        v4i c02 = a00 < a22;
        t = a00; a00 = sel4(c02, a22, a00); a22 = sel4(c02, t, a22);
        t = v00; v00 = sel4(c02, v02, v00); v02 = sel4(c02, -t, v02);
        t = v10; v10 = sel4(c02, v12, v10); v12 = sel4(c02, -t, v12);
        t = v20; v20 = sel4(c02, v22, v20); v22 = sel4(c02, -t, v22);
    }
    {
        v4i c12 = a11 < a22;
        t = a11; a11 = sel4(c12, a22, a11); a22 = sel4(c12, t, a22);
        t = v01; v01 = sel4(c12, v02, v01); v02 = sel4(c12, -t, v02);
        t = v11; v11 = sel4(c12, v12, v11); v12 = sel4(c12, -t, v12);
        t = v21; v21 = sel4(c12, v22, v21); v22 = sel4(c12, -t, v22);
    }

    v4f b00 = m00*v00 + m01*v10 + m02*v20;
    v4f b10 = m10*v00 + m11*v10 + m12*v20;
    v4f b20 = m20*v00 + m21*v10 + m22*v20;
    v4f b01 = m00*v01 + m01*v11 + m02*v21;
    v4f b11 = m10*v01 + m11*v11 + m12*v21;
    v4f b21 = m20*v01 + m21*v11 + m22*v21;

    v4f n1 = b00*b00 + b10*b10 + b20*b20;
    v4f i1 = rsq4(n1);
    v4i ok1 = n1 > (v4f)1e-30f;
    i1 = sel4(ok1, i1, (v4f)0.0f);
    v4f u00 = b00*i1, u10 = b10*i1, u20 = b20*i1;

    v4f d12 = b01*u00 + b11*u10 + b21*u20;
    v4f q0 = b01 - d12*u00;
    v4f q1 = b11 - d12*u10;
    v4f q2 = b21 - d12*u20;
    v4f n2 = q0*q0 + q1*q1 + q2*q2;
    v4f i2 = rsq4(n2);
    v4i ok2 = n2 > (v4f)1e-30f;
    i2 = sel4(ok2, i2, (v4f)0.0f);
    v4f u01 = q0*i2, u11 = q1*i2, u21 = q2*i2;

    v4f u02 = u10*u21 - u20*u11;
    v4f u12 = u20*u01 - u00*u21;
    v4f u22 = u00*u11 - u10*u01;

    r00 = u00*v00 + u01*v01 + u02*v02;
    r01 = u00*v10 + u01*v11 + u02*v12;
    r02 = u00*v20 + u01*v21 + u02*v22;
    r10 = u10*v00 + u11*v01 + u12*v02;
    r11 = u10*v10 + u11*v11 + u12*v12;
    r12 = u10*v20 + u11*v21 + u12*v22;
    r20 = u20*v00 + u21*v01 + u22*v02;
    r21 = u20*v10 + u21*v11 + u22*v12;
    r22 = u20*v20 + u21*v21 + u22*v22;
}

static __device__ __forceinline__ float4 ld_f4(const float* __restrict__ x, long f, long ntotf){
    if (f + 4 <= ntotf) return *(const float4*)(x + f);
    float4 r = make_float4(0.f, 0.f, 0.f, 0.f);
    if (f     < ntotf) r.x = x[f];
    if (f + 1 < ntotf) r.y = x[f + 1];
    if (f + 2 < ntotf) r.z = x[f + 2];
    if (f + 3 < ntotf) r.w = x[f + 3];
    return r;
}
static __device__ __forceinline__ void st_f4(float* __restrict__ o, long f, float4 v, long ntotf){
    if (f + 4 <= ntotf) { *(float4*)(o + f) = v; return; }
    if (f     < ntotf) o[f]     = v.x;
    if (f + 1 < ntotf) o[f + 1] = v.y;
    if (f + 2 < ntotf) o[f + 2] = v.z;
    if (f + 3 < ntotf) o[f + 3] = v.w;
}

// Wave-decoupled one-shot kernel, 4 matrices per lane (v4f). Each wave owns
// a private 9.2 KB LDS region; no __syncthreads anywhere (wave-local
// s_waitcnt lgkmcnt(0) fences the cross-lane LDS shuffles). 36.9 KB/block ->
// 4 blocks/CU = 16 waves/CU; the occupancy loss vs deeper configs is repaid
// by 2x instruction-level parallelism per wave (two v_pk chains).
// NO launch-bounds min-wave cap (rounds 9/10: caps spill the staging regs).
__global__ __launch_bounds__(TPB) void svdo_kernel(const float* __restrict__ x,
                                                   float* __restrict__ out,
                                                   int nmat)
{
    __shared__ float lds[4][FPW];       // 36864 B / block
    const int lane = threadIdx.x & 63;
    const int wv   = threadIdx.x >> 6;
    const long mbase = (long)blockIdx.x * MPB + (long)wv * MPW;
    if (mbase >= nmat) return;
    const long fb    = mbase * 9;
    const long ntotf = (long)nmat * 9;
    float* L = lds[wv];

    // Stage in: 576 float4 per wave region (9 per lane), lane-consecutive.
    #pragma unroll
    for (int k = 0; k < 9; ++k) {
        const int idx = lane + k * 64;
        float4 v = ld_f4(x, fb + (long)idx * 4, ntotf);
        *(float4*)&L[idx * 4] = v;
    }
    asm volatile("s_waitcnt lgkmcnt(0)" ::: "memory");
    __builtin_amdgcn_sched_barrier(0);

    // Gather 4 matrices per lane (stride-9 floats: 2 lanes/bank, free).
    const float* p0 = &L[lane * 9];
    const float* p1 = &L[(lane +  64) * 9];
    const float* p2 = &L[(lane + 128) * 9];
    const float* p3 = &L[(lane + 192) * 9];
    v4f m00 = {p0[0],p1[0],p2[0],p3[0]}, m01 = {p0[1],p1[1],p2[1],p3[1]},
        m02 = {p0[2],p1[2],p2[2],p3[2]};
    v4f m10 = {p0[3],p1[3],p2[3],p3[3]}, m11 = {p0[4],p1[4],p2[4],p3[4]},
        m12 = {p0[5],p1[5],p2[5],p3[5]};
    v4f m20 = {p0[6],p1[6],p2[6],p3[6]}, m21 = {p0[7],p1[7],p2[7],p3[7]},
        m22 = {p0[8],p1[8],p2[8],p3[8]};

    v4f r00, r01, r02, r10, r11, r12, r20, r21, r22;
    solve4(m00, m01, m02, m10, m11, m12, m20, m21, m22,
           r00, r01, r02, r10, r11, r12, r20, r21, r22);

    // Scatter results back to own region.
    {
        float* o0 = &L[lane * 9];
        o0[0]=r00.x; o0[1]=r01.x; o0[2]=r02.x;
        o0[3]=r10.x; o0[4]=r11.x; o0[5]=r12.x;
        o0[6]=r20.x; o0[7]=r21.x; o0[8]=r22.x;
        float* o1 = &L[(lane + 64) * 9];
        o1[0]=r00.y; o1[1]=r01.y; o1[2]=r02.y;
        o1[3]=r10.y; o1[4]=r11.y; o1[5]=r12.y;
        o1[6]=r20.y; o1[7]=r21.y; o1[8]=r22.y;
        float* o2 = &L[(lane + 128) * 9];
        o2[0]=r00.z; o2[1]=r01.z; o2[2]=r02.z;
        o2[3]=r10.z; o2[4]=r11.z; o2[5]=r12.z;
        o2[6]=r20.z; o2[7]=r21.z; o2[8]=r22.z;
        float* o3 = &L[(lane + 192) * 9];
        o3[0]=r00.w; o3[1]=r01.w; o3[2]=r02.w;
        o3[3]=r10.w; o3[4]=r11.w; o3[5]=r12.w;
        o3[6]=r20.w; o3[7]=r21.w; o3[8]=r22.w;
    }
    asm volatile("s_waitcnt lgkmcnt(0)" ::: "memory");
    __builtin_amdgcn_sched_barrier(0);

    // Stage out: coalesced float4 stores.
    #pragma unroll
    for (int k = 0; k < 9; ++k) {
        const int idx = lane + k * 64;
        float4 v = *(const float4*)&L[idx * 4];
        st_f4(out, fb + (long)idx * 4, v, ntotf);
    }
}

extern "C" void kernel_launch(void* const* d_in, const int* in_sizes, int n_in,
                              void* d_out, int out_size, void* d_ws, size_t ws_size,
                              hipStream_t stream)
{
    (void)n_in; (void)d_ws; (void)ws_size; (void)out_size;
    const float* x = (const float*)d_in[0];
    float* out = (float*)d_out;
    const int nmat = in_sizes[0] / 9;
    const int grid = (nmat + MPB - 1) / MPB;
    svdo_kernel<<<grid, TPB, 0, stream>>>(x, out, nmat);
}